// Round 1
// baseline (631.206 us; speedup 1.0000x reference)
//
#include <hip/hip_runtime.h>
#include <hip/hip_bf16.h>

// Linear4bit NF4: y[2048,11008] = x[2048,4096] @ dequant(W)[11008,4096]^T + bias
// Fused kernel: dequantize W tiles into LDS (bf16), x tiles fp32->bf16 into LDS,
// 128x128 block tile, BK=64, 4 waves each doing 4x4 of mfma_f32_16x16x32_bf16.

#define IN_F   4096
#define OUT_F  11008
#define M_ROWS 2048
#define BM 128
#define BN 128
#define BK 64
#define LDSS 72   // padded LDS row stride in bf16 elems (144 B = 36 banks -> 2-way, free)

typedef short  s16x8 __attribute__((ext_vector_type(8)));
typedef unsigned short u16x8 __attribute__((ext_vector_type(8)));
typedef float  f32x4 __attribute__((ext_vector_type(4)));

__device__ const float NF4_C[16] = {
    -1.0f, -0.6961928009986877f, -0.5250730514526367f, -0.39491748809814453f,
    -0.28444138169288635f, -0.18477343022823334f, -0.09105003625154495f, 0.0f,
    0.07958029955625534f, 0.16093020141124725f, 0.24611230194568634f,
    0.33791524171829224f, 0.44070982933044434f, 0.5626170039176941f,
    0.7229568362236023f, 1.0f};

// fp32 -> bf16 bits, round-to-nearest-even (header-version-proof)
static __device__ __forceinline__ unsigned short f2bf(float f) {
    union { float f; unsigned int u; } c;
    c.f = f;
    unsigned int u = c.u;
    u += 0x7fffu + ((u >> 16) & 1u);
    return (unsigned short)(u >> 16);
}

__global__ __launch_bounds__(256, 2)
void nf4_linear_kernel(const float* __restrict__ x,
                       const int* __restrict__ packed,
                       const float* __restrict__ absmax,
                       const float* __restrict__ bias,
                       float* __restrict__ out) {
    __shared__ __align__(16) unsigned short As[BM * LDSS];
    __shared__ __align__(16) unsigned short Bs[BN * LDSS];
    __shared__ float2 tab[256];   // byte -> (NF4[hi], NF4[lo])

    const int tid  = threadIdx.x;
    const int lane = tid & 63;
    const int wave = tid >> 6;
    const int quad = lane >> 4;
    const int l16  = lane & 15;
    const int wm = wave & 1;      // wave's 64-row slice of the 128-row tile
    const int wn = wave >> 1;     // wave's 64-col slice

    const int mBase = blockIdx.y * BM;
    const int nBase = blockIdx.x * BN;

    // build dequant table: one float2 per byte value
    tab[tid] = make_float2(NF4_C[tid >> 4], NF4_C[tid & 15]);

    f32x4 acc[4][4];
#pragma unroll
    for (int mi = 0; mi < 4; ++mi)
#pragma unroll
        for (int ni = 0; ni < 4; ++ni)
            acc[mi][ni] = (f32x4){0.f, 0.f, 0.f, 0.f};

    // B staging assignment: 2 threads per W row, 16 packed int32 (=32 weights) each
    const int brow  = tid >> 1;
    const int bhalf = tid & 1;
    const int ng    = nBase + brow;

    for (int kt = 0; kt < IN_F / BK; ++kt) {
        const int k0 = kt * BK;
        __syncthreads();  // also covers the table build on iter 0

        // ---- stage A: x[mBase..+127][k0..+63] fp32 -> bf16 LDS ----
#pragma unroll
        for (int i = 0; i < 4; ++i) {
            int gid = tid + i * 256;      // 0..1023
            int row = gid >> 3;           // 0..127
            int c8  = gid & 7;            // chunk of 8 floats
            const float4* src = reinterpret_cast<const float4*>(
                x + (size_t)(mBase + row) * IN_F + k0 + c8 * 8);
            float4 v0 = src[0];
            float4 v1 = src[1];
            u16x8 o;
            o[0] = f2bf(v0.x); o[1] = f2bf(v0.y); o[2] = f2bf(v0.z); o[3] = f2bf(v0.w);
            o[4] = f2bf(v1.x); o[5] = f2bf(v1.y); o[6] = f2bf(v1.z); o[7] = f2bf(v1.w);
            *reinterpret_cast<u16x8*>(&As[row * LDSS + c8 * 8]) = o;
        }

        // ---- stage B: dequant W[nBase..+127][k0..+63] -> bf16 LDS ----
        {
            const float scale = absmax[(size_t)ng * 64 + (k0 >> 6)];
            const int4* bp = reinterpret_cast<const int4*>(
                packed + (size_t)ng * (IN_F / 2) + (k0 >> 1) + bhalf * 16);
            const int colw = bhalf * 32;
#pragma unroll
            for (int c = 0; c < 4; ++c) {
                int4 v = bp[c];
                int vs[4] = {v.x, v.y, v.z, v.w};
                unsigned int ow[4];
#pragma unroll
                for (int j = 0; j < 4; ++j) {
                    float2 t = tab[vs[j] & 0xFF];   // x: even k (hi nibble), y: odd k (lo)
                    ow[j] = (unsigned int)f2bf(t.x * scale)
                          | ((unsigned int)f2bf(t.y * scale) << 16);
                }
                *reinterpret_cast<uint4*>(&Bs[brow * LDSS + colw + c * 8]) =
                    *reinterpret_cast<const uint4*>(ow);
            }
        }
        __syncthreads();

        // ---- MFMA: 2 k-steps of 32, 4x4 tiles of 16x16 per wave ----
#pragma unroll
        for (int kk = 0; kk < 2; ++kk) {
            const int kof = kk * 32 + quad * 8;
            s16x8 af[4], bfr[4];
#pragma unroll
            for (int mi = 0; mi < 4; ++mi)
                af[mi] = *reinterpret_cast<const s16x8*>(
                    &As[(wm * 64 + mi * 16 + l16) * LDSS + kof]);
#pragma unroll
            for (int ni = 0; ni < 4; ++ni)
                bfr[ni] = *reinterpret_cast<const s16x8*>(
                    &Bs[(wn * 64 + ni * 16 + l16) * LDSS + kof]);
#pragma unroll
            for (int mi = 0; mi < 4; ++mi)
#pragma unroll
                for (int ni = 0; ni < 4; ++ni)
                    acc[mi][ni] = __builtin_amdgcn_mfma_f32_16x16x32_bf16(
                        af[mi], bfr[ni], acc[mi][ni], 0, 0, 0);
        }
    }

    // ---- epilogue: C/D layout row=quad*4+r, col=l16 ----
    float bv[4];
#pragma unroll
    for (int ni = 0; ni < 4; ++ni)
        bv[ni] = bias[nBase + wn * 64 + ni * 16 + l16];
#pragma unroll
    for (int mi = 0; mi < 4; ++mi) {
        const int rbase = mBase + wm * 64 + mi * 16 + quad * 4;
#pragma unroll
        for (int ni = 0; ni < 4; ++ni) {
            const int col = nBase + wn * 64 + ni * 16 + l16;
#pragma unroll
            for (int r = 0; r < 4; ++r)
                out[(size_t)(rbase + r) * OUT_F + col] = acc[mi][ni][r] + bv[ni];
        }
    }
}

extern "C" void kernel_launch(void* const* d_in, const int* in_sizes, int n_in,
                              void* d_out, int out_size, void* d_ws, size_t ws_size,
                              hipStream_t stream) {
    const float* x      = (const float*)d_in[0];
    const int*   packed = (const int*)d_in[1];
    const float* absmax = (const float*)d_in[2];
    const float* bias   = (const float*)d_in[3];
    float* out = (float*)d_out;

    dim3 grid(OUT_F / BN, M_ROWS / BM);   // (86, 16)
    nf4_linear_kernel<<<grid, dim3(256), 0, stream>>>(x, packed, absmax, bias, out);
}

// Round 2
// 431.115 us; speedup vs baseline: 1.4641x; 1.4641x over previous
//
#include <hip/hip_runtime.h>
#include <hip/hip_bf16.h>

// Linear4bit NF4: y[2048,11008] = x[2048,4096] @ dequant(W)[11008,4096]^T + bias
// Three-phase: (1) x fp32->bf16 into ws, (2) NF4 dequant W -> bf16 into ws,
// (3) m97-style bf16 GEMM (global_load_lds width=16, 128x128x64 tile).
// Fallback: fused round-1 kernel if ws_size is too small.

#define IN_F   4096
#define OUT_F  11008
#define M_ROWS 2048
#define BM 128
#define BN 128
#define BK 64
#define LDSS 72   // fused-fallback padded stride

typedef short  s16x8 __attribute__((ext_vector_type(8)));
typedef unsigned short u16x8 __attribute__((ext_vector_type(8)));
typedef float  f32x4 __attribute__((ext_vector_type(4)));

__device__ const float NF4_C[16] = {
    -1.0f, -0.6961928009986877f, -0.5250730514526367f, -0.39491748809814453f,
    -0.28444138169288635f, -0.18477343022823334f, -0.09105003625154495f, 0.0f,
    0.07958029955625534f, 0.16093020141124725f, 0.24611230194568634f,
    0.33791524171829224f, 0.44070982933044434f, 0.5626170039176941f,
    0.7229568362236023f, 1.0f};

static __device__ __forceinline__ unsigned short f2bf(float f) {
    union { float f; unsigned int u; } c;
    c.f = f;
    unsigned int u = c.u;
    u += 0x7fffu + ((u >> 16) & 1u);
    return (unsigned short)(u >> 16);
}

static __device__ __forceinline__ void gload_lds16(const void* g, void* l) {
    __builtin_amdgcn_global_load_lds(
        (const __attribute__((address_space(1))) void*)g,
        (__attribute__((address_space(3))) void*)l, 16, 0, 0);
}

// ---------------- phase 1: x fp32 -> bf16 ----------------
__global__ __launch_bounds__(256)
void convert_x_kernel(const float* __restrict__ x, unsigned short* __restrict__ xb) {
    const size_t t = (size_t)blockIdx.x * 256 + threadIdx.x;   // 1,048,576 threads, 8 elems each
    const float4* src = reinterpret_cast<const float4*>(x) + t * 2;
    float4 v0 = src[0];
    float4 v1 = src[1];
    u16x8 o;
    o[0] = f2bf(v0.x); o[1] = f2bf(v0.y); o[2] = f2bf(v0.z); o[3] = f2bf(v0.w);
    o[4] = f2bf(v1.x); o[5] = f2bf(v1.y); o[6] = f2bf(v1.z); o[7] = f2bf(v1.w);
    *reinterpret_cast<u16x8*>(xb + t * 8) = o;
}

// ---------------- phase 2: NF4 -> bf16 W ----------------
__global__ __launch_bounds__(256)
void dequant_w_kernel(const int* __restrict__ packed, const float* __restrict__ absmax,
                      unsigned short* __restrict__ wb) {
    __shared__ float2 tab[256];
    tab[threadIdx.x] = make_float2(NF4_C[threadIdx.x >> 4], NF4_C[threadIdx.x & 15]);
    __syncthreads();

    const size_t t = (size_t)blockIdx.x * 256 + threadIdx.x;   // 2,818,048 threads
    const int4* p = reinterpret_cast<const int4*>(packed) + t * 2;  // 8 ints = 16 weights
    int4 a = p[0];
    int4 b = p[1];
    const float s = absmax[t >> 2];   // 16 weights, 64-aligned block => single scale

    int vs[8] = {a.x, a.y, a.z, a.w, b.x, b.y, b.z, b.w};
    unsigned int ow[8];
#pragma unroll
    for (int j = 0; j < 8; ++j) {
        float2 tv = tab[vs[j] & 0xFF];
        ow[j] = (unsigned int)f2bf(tv.x * s) | ((unsigned int)f2bf(tv.y * s) << 16);
    }
    uint4* dst = reinterpret_cast<uint4*>(wb + t * 16);
    dst[0] = make_uint4(ow[0], ow[1], ow[2], ow[3]);
    dst[1] = make_uint4(ow[4], ow[5], ow[6], ow[7]);
}

// ---------------- phase 3: bf16 GEMM, m97 structure ----------------
__global__ __launch_bounds__(256, 2)
void gemm_bt_kernel(const unsigned short* __restrict__ xb,   // [2048,4096] bf16
                    const unsigned short* __restrict__ wb,   // [11008,4096] bf16
                    const float* __restrict__ bias,
                    float* __restrict__ out) {
    __shared__ __align__(16) unsigned short As[BM * BK];   // unpadded: global_load_lds layout
    __shared__ __align__(16) unsigned short Bs[BN * BK];

    const int tid  = threadIdx.x;
    const int lane = tid & 63;
    const int wave = tid >> 6;
    const int quad = lane >> 4;
    const int l16  = lane & 15;
    const int wm = wave & 1;
    const int wn = wave >> 1;

    const int mBase = blockIdx.y * BM;
    const int nBase = blockIdx.x * BN;

    // staging: thread -> (tile row tid/8 + 32*i, col (tid%8)*8 elems), 16 B each
    const int srow = tid >> 3;
    const int scol = (tid & 7) * 8;

    f32x4 acc[4][4];
#pragma unroll
    for (int mi = 0; mi < 4; ++mi)
#pragma unroll
        for (int ni = 0; ni < 4; ++ni)
            acc[mi][ni] = (f32x4){0.f, 0.f, 0.f, 0.f};

    const unsigned short* aSrc = xb + (size_t)(mBase + srow) * IN_F + scol;
    const unsigned short* bSrc = wb + (size_t)(nBase + srow) * IN_F + scol;

    for (int kt = 0; kt < IN_F / BK; ++kt) {
        const int k0 = kt * BK;
        __syncthreads();
#pragma unroll
        for (int i = 0; i < 4; ++i)
            gload_lds16(aSrc + (size_t)i * 32 * IN_F + k0, &As[(i * 32 + srow) * BK + scol]);
#pragma unroll
        for (int i = 0; i < 4; ++i)
            gload_lds16(bSrc + (size_t)i * 32 * IN_F + k0, &Bs[(i * 32 + srow) * BK + scol]);
        __syncthreads();

#pragma unroll
        for (int kk = 0; kk < 2; ++kk) {
            const int kof = kk * 32 + quad * 8;
            s16x8 af[4], bfr[4];
#pragma unroll
            for (int mi = 0; mi < 4; ++mi)
                af[mi] = *reinterpret_cast<const s16x8*>(
                    &As[(wm * 64 + mi * 16 + l16) * BK + kof]);
#pragma unroll
            for (int ni = 0; ni < 4; ++ni)
                bfr[ni] = *reinterpret_cast<const s16x8*>(
                    &Bs[(wn * 64 + ni * 16 + l16) * BK + kof]);
#pragma unroll
            for (int mi = 0; mi < 4; ++mi)
#pragma unroll
                for (int ni = 0; ni < 4; ++ni)
                    acc[mi][ni] = __builtin_amdgcn_mfma_f32_16x16x32_bf16(
                        af[mi], bfr[ni], acc[mi][ni], 0, 0, 0);
        }
    }

    float bv[4];
#pragma unroll
    for (int ni = 0; ni < 4; ++ni)
        bv[ni] = bias[nBase + wn * 64 + ni * 16 + l16];
#pragma unroll
    for (int mi = 0; mi < 4; ++mi) {
        const int rbase = mBase + wm * 64 + mi * 16 + quad * 4;
#pragma unroll
        for (int ni = 0; ni < 4; ++ni) {
            const int col = nBase + wn * 64 + ni * 16 + l16;
#pragma unroll
            for (int r = 0; r < 4; ++r)
                out[(size_t)(rbase + r) * OUT_F + col] = acc[mi][ni][r] + bv[ni];
        }
    }
}

// ---------------- fallback: round-1 fused kernel ----------------
__global__ __launch_bounds__(256, 2)
void nf4_linear_fused(const float* __restrict__ x,
                      const int* __restrict__ packed,
                      const float* __restrict__ absmax,
                      const float* __restrict__ bias,
                      float* __restrict__ out) {
    __shared__ __align__(16) unsigned short As[BM * LDSS];
    __shared__ __align__(16) unsigned short Bs[BN * LDSS];
    __shared__ float2 tab[256];

    const int tid  = threadIdx.x;
    const int lane = tid & 63;
    const int wave = tid >> 6;
    const int quad = lane >> 4;
    const int l16  = lane & 15;
    const int wm = wave & 1;
    const int wn = wave >> 1;
    const int mBase = blockIdx.y * BM;
    const int nBase = blockIdx.x * BN;

    tab[tid] = make_float2(NF4_C[tid >> 4], NF4_C[tid & 15]);

    f32x4 acc[4][4];
#pragma unroll
    for (int mi = 0; mi < 4; ++mi)
#pragma unroll
        for (int ni = 0; ni < 4; ++ni)
            acc[mi][ni] = (f32x4){0.f, 0.f, 0.f, 0.f};

    const int brow  = tid >> 1;
    const int bhalf = tid & 1;
    const int ng    = nBase + brow;

    for (int kt = 0; kt < IN_F / BK; ++kt) {
        const int k0 = kt * BK;
        __syncthreads();
#pragma unroll
        for (int i = 0; i < 4; ++i) {
            int gid = tid + i * 256;
            int row = gid >> 3;
            int c8  = gid & 7;
            const float4* src = reinterpret_cast<const float4*>(
                x + (size_t)(mBase + row) * IN_F + k0 + c8 * 8);
            float4 v0 = src[0];
            float4 v1 = src[1];
            u16x8 o;
            o[0] = f2bf(v0.x); o[1] = f2bf(v0.y); o[2] = f2bf(v0.z); o[3] = f2bf(v0.w);
            o[4] = f2bf(v1.x); o[5] = f2bf(v1.y); o[6] = f2bf(v1.z); o[7] = f2bf(v1.w);
            *reinterpret_cast<u16x8*>(&As[row * LDSS + c8 * 8]) = o;
        }
        {
            const float scale = absmax[(size_t)ng * 64 + (k0 >> 6)];
            const int4* bp = reinterpret_cast<const int4*>(
                packed + (size_t)ng * (IN_F / 2) + (k0 >> 1) + bhalf * 16);
            const int colw = bhalf * 32;
#pragma unroll
            for (int c = 0; c < 4; ++c) {
                int4 v = bp[c];
                int vs[4] = {v.x, v.y, v.z, v.w};
                unsigned int ow[4];
#pragma unroll
                for (int j = 0; j < 4; ++j) {
                    float2 t = tab[vs[j] & 0xFF];
                    ow[j] = (unsigned int)f2bf(t.x * scale)
                          | ((unsigned int)f2bf(t.y * scale) << 16);
                }
                *reinterpret_cast<uint4*>(&Bs[brow * LDSS + colw + c * 8]) =
                    *reinterpret_cast<const uint4*>(ow);
            }
        }
        __syncthreads();

#pragma unroll
        for (int kk = 0; kk < 2; ++kk) {
            const int kof = kk * 32 + quad * 8;
            s16x8 af[4], bfr[4];
#pragma unroll
            for (int mi = 0; mi < 4; ++mi)
                af[mi] = *reinterpret_cast<const s16x8*>(
                    &As[(wm * 64 + mi * 16 + l16) * LDSS + kof]);
#pragma unroll
            for (int ni = 0; ni < 4; ++ni)
                bfr[ni] = *reinterpret_cast<const s16x8*>(
                    &Bs[(wn * 64 + ni * 16 + l16) * LDSS + kof]);
#pragma unroll
            for (int mi = 0; mi < 4; ++mi)
#pragma unroll
                for (int ni = 0; ni < 4; ++ni)
                    acc[mi][ni] = __builtin_amdgcn_mfma_f32_16x16x32_bf16(
                        af[mi], bfr[ni], acc[mi][ni], 0, 0, 0);
        }
    }

    float bv[4];
#pragma unroll
    for (int ni = 0; ni < 4; ++ni)
        bv[ni] = bias[nBase + wn * 64 + ni * 16 + l16];
#pragma unroll
    for (int mi = 0; mi < 4; ++mi) {
        const int rbase = mBase + wm * 64 + mi * 16 + quad * 4;
#pragma unroll
        for (int ni = 0; ni < 4; ++ni) {
            const int col = nBase + wn * 64 + ni * 16 + l16;
#pragma unroll
            for (int r = 0; r < 4; ++r)
                out[(size_t)(rbase + r) * OUT_F + col] = acc[mi][ni][r] + bv[ni];
        }
    }
}

extern "C" void kernel_launch(void* const* d_in, const int* in_sizes, int n_in,
                              void* d_out, int out_size, void* d_ws, size_t ws_size,
                              hipStream_t stream) {
    const float* x      = (const float*)d_in[0];
    const int*   packed = (const int*)d_in[1];
    const float* absmax = (const float*)d_in[2];
    const float* bias   = (const float*)d_in[3];
    float* out = (float*)d_out;

    const size_t xb_bytes = (size_t)M_ROWS * IN_F * 2;          // 16,777,216
    const size_t wb_bytes = (size_t)OUT_F * IN_F * 2;           // 90,177,536
    if (ws_size >= xb_bytes + wb_bytes) {
        unsigned short* xb = (unsigned short*)d_ws;
        unsigned short* wb = (unsigned short*)((char*)d_ws + xb_bytes);
        convert_x_kernel<<<dim3((M_ROWS * IN_F) / (256 * 8)), dim3(256), 0, stream>>>(x, xb);
        dequant_w_kernel<<<dim3((OUT_F * IN_F / 2) / (256 * 8)), dim3(256), 0, stream>>>(
            packed, absmax, wb);
        gemm_bt_kernel<<<dim3(OUT_F / BN, M_ROWS / BM), dim3(256), 0, stream>>>(
            xb, wb, bias, out);
    } else {
        nf4_linear_fused<<<dim3(OUT_F / BN, M_ROWS / BM), dim3(256), 0, stream>>>(
            x, packed, absmax, bias, out);
    }
}

// Round 3
// 396.196 us; speedup vs baseline: 1.5932x; 1.0881x over previous
//
#include <hip/hip_runtime.h>
#include <hip/hip_bf16.h>

// Linear4bit NF4: y[2048,11008] = x[2048,4096] @ dequant(W)[11008,4096]^T + bias
// Phase 1 (merged): x fp32->bf16, NF4 dequant W->bf16, both into d_ws.
//   Non-temporal loads on read-once inputs to keep wb L3-resident for the GEMM.
// Phase 2: m97-style bf16 GEMM (global_load_lds width=16, 128x128x64 tile),
//   grid swapped to (M-tiles, N-tiles) so consecutive blocks share a B-tile
//   and the re-read matrix is A (16.8 MB, cache-resident) not B (90 MB).

#define IN_F   4096
#define OUT_F  11008
#define M_ROWS 2048
#define BM 128
#define BN 128
#define BK 64
#define LDSS 72   // fused-fallback padded stride

typedef short  s16x8 __attribute__((ext_vector_type(8)));
typedef unsigned short u16x8 __attribute__((ext_vector_type(8)));
typedef float  f32x4 __attribute__((ext_vector_type(4)));
typedef int    i32x4 __attribute__((ext_vector_type(4)));
typedef unsigned int u32x4 __attribute__((ext_vector_type(4)));

__device__ const float NF4_C[16] = {
    -1.0f, -0.6961928009986877f, -0.5250730514526367f, -0.39491748809814453f,
    -0.28444138169288635f, -0.18477343022823334f, -0.09105003625154495f, 0.0f,
    0.07958029955625534f, 0.16093020141124725f, 0.24611230194568634f,
    0.33791524171829224f, 0.44070982933044434f, 0.5626170039176941f,
    0.7229568362236023f, 1.0f};

static __device__ __forceinline__ unsigned short f2bf(float f) {
    union { float f; unsigned int u; } c;
    c.f = f;
    unsigned int u = c.u;
    u += 0x7fffu + ((u >> 16) & 1u);
    return (unsigned short)(u >> 16);
}

static __device__ __forceinline__ void gload_lds16(const void* g, void* l) {
    __builtin_amdgcn_global_load_lds(
        (const __attribute__((address_space(1))) void*)g,
        (__attribute__((address_space(3))) void*)l, 16, 0, 0);
}

// ---------------- phase 1 (merged): dequant W + convert x ----------------
#define DQ_BLOCKS 11008                        // OUT_F*IN_F/2 / (256*8) int32s
#define CV_BLOCKS 4096                         // M_ROWS*IN_F / (256*8) floats

__global__ __launch_bounds__(256)
void prep_kernel(const float* __restrict__ x,
                 const int* __restrict__ packed,
                 const float* __restrict__ absmax,
                 unsigned short* __restrict__ xb,
                 unsigned short* __restrict__ wb) {
    if (blockIdx.x < DQ_BLOCKS) {
        __shared__ float2 tab[256];
        tab[threadIdx.x] = make_float2(NF4_C[threadIdx.x >> 4], NF4_C[threadIdx.x & 15]);
        __syncthreads();

        const size_t t = (size_t)blockIdx.x * 256 + threadIdx.x;
        const i32x4* p = reinterpret_cast<const i32x4*>(packed) + t * 2;  // 8 ints = 16 weights
        i32x4 a = __builtin_nontemporal_load(p);
        i32x4 b = __builtin_nontemporal_load(p + 1);
        const float s = absmax[t >> 2];   // 16 aligned weights => one 64-block scale

        int vs[8] = {a[0], a[1], a[2], a[3], b[0], b[1], b[2], b[3]};
        unsigned int ow[8];
#pragma unroll
        for (int j = 0; j < 8; ++j) {
            float2 tv = tab[vs[j] & 0xFF];
            ow[j] = (unsigned int)f2bf(tv.x * s) | ((unsigned int)f2bf(tv.y * s) << 16);
        }
        u32x4* dst = reinterpret_cast<u32x4*>(wb + t * 16);
        dst[0] = (u32x4){ow[0], ow[1], ow[2], ow[3]};
        dst[1] = (u32x4){ow[4], ow[5], ow[6], ow[7]};
    } else {
        const size_t t = (size_t)(blockIdx.x - DQ_BLOCKS) * 256 + threadIdx.x;
        const f32x4* src = reinterpret_cast<const f32x4*>(x) + t * 2;
        f32x4 v0 = __builtin_nontemporal_load(src);
        f32x4 v1 = __builtin_nontemporal_load(src + 1);
        u16x8 o;
        o[0] = f2bf(v0[0]); o[1] = f2bf(v0[1]); o[2] = f2bf(v0[2]); o[3] = f2bf(v0[3]);
        o[4] = f2bf(v1[0]); o[5] = f2bf(v1[1]); o[6] = f2bf(v1[2]); o[7] = f2bf(v1[3]);
        *reinterpret_cast<u16x8*>(xb + t * 8) = o;
    }
}

// ---------------- phase 2: bf16 GEMM, m97 structure ----------------
__global__ __launch_bounds__(256, 2)
void gemm_bt_kernel(const unsigned short* __restrict__ xb,   // [2048,4096] bf16
                    const unsigned short* __restrict__ wb,   // [11008,4096] bf16
                    const float* __restrict__ bias,
                    float* __restrict__ out) {
    __shared__ __align__(16) unsigned short As[BM * BK];   // unpadded: global_load_lds layout
    __shared__ __align__(16) unsigned short Bs[BN * BK];

    const int tid  = threadIdx.x;
    const int lane = tid & 63;
    const int wave = tid >> 6;
    const int quad = lane >> 4;
    const int l16  = lane & 15;
    const int wm = wave & 1;
    const int wn = wave >> 1;

    // grid is (M-tiles=16, N-tiles=86); x varies fastest so 16 consecutive
    // blocks share one B-tile -> B read ~once from HBM, A re-read hits cache.
    const int mBase = blockIdx.x * BM;
    const int nBase = blockIdx.y * BN;

    const int srow = tid >> 3;
    const int scol = (tid & 7) * 8;

    f32x4 acc[4][4];
#pragma unroll
    for (int mi = 0; mi < 4; ++mi)
#pragma unroll
        for (int ni = 0; ni < 4; ++ni)
            acc[mi][ni] = (f32x4){0.f, 0.f, 0.f, 0.f};

    const unsigned short* aSrc = xb + (size_t)(mBase + srow) * IN_F + scol;
    const unsigned short* bSrc = wb + (size_t)(nBase + srow) * IN_F + scol;

    for (int kt = 0; kt < IN_F / BK; ++kt) {
        const int k0 = kt * BK;
        __syncthreads();
#pragma unroll
        for (int i = 0; i < 4; ++i)
            gload_lds16(aSrc + (size_t)i * 32 * IN_F + k0, &As[(i * 32 + srow) * BK + scol]);
#pragma unroll
        for (int i = 0; i < 4; ++i)
            gload_lds16(bSrc + (size_t)i * 32 * IN_F + k0, &Bs[(i * 32 + srow) * BK + scol]);
        __syncthreads();

#pragma unroll
        for (int kk = 0; kk < 2; ++kk) {
            const int kof = kk * 32 + quad * 8;
            s16x8 af[4], bfr[4];
#pragma unroll
            for (int mi = 0; mi < 4; ++mi)
                af[mi] = *reinterpret_cast<const s16x8*>(
                    &As[(wm * 64 + mi * 16 + l16) * BK + kof]);
#pragma unroll
            for (int ni = 0; ni < 4; ++ni)
                bfr[ni] = *reinterpret_cast<const s16x8*>(
                    &Bs[(wn * 64 + ni * 16 + l16) * BK + kof]);
#pragma unroll
            for (int mi = 0; mi < 4; ++mi)
#pragma unroll
                for (int ni = 0; ni < 4; ++ni)
                    acc[mi][ni] = __builtin_amdgcn_mfma_f32_16x16x32_bf16(
                        af[mi], bfr[ni], acc[mi][ni], 0, 0, 0);
        }
    }

    float bv[4];
#pragma unroll
    for (int ni = 0; ni < 4; ++ni)
        bv[ni] = bias[nBase + wn * 64 + ni * 16 + l16];
#pragma unroll
    for (int mi = 0; mi < 4; ++mi) {
        const int rbase = mBase + wm * 64 + mi * 16 + quad * 4;
#pragma unroll
        for (int ni = 0; ni < 4; ++ni) {
            const int col = nBase + wn * 64 + ni * 16 + l16;
#pragma unroll
            for (int r = 0; r < 4; ++r)
                __builtin_nontemporal_store(acc[mi][ni][r] + bv[ni],
                    &out[(size_t)(rbase + r) * OUT_F + col]);
        }
    }
}

// ---------------- fallback: round-1 fused kernel (small ws) ----------------
__global__ __launch_bounds__(256, 2)
void nf4_linear_fused(const float* __restrict__ x,
                      const int* __restrict__ packed,
                      const float* __restrict__ absmax,
                      const float* __restrict__ bias,
                      float* __restrict__ out) {
    __shared__ __align__(16) unsigned short As[BM * LDSS];
    __shared__ __align__(16) unsigned short Bs[BN * LDSS];
    __shared__ float2 tab[256];

    const int tid  = threadIdx.x;
    const int lane = tid & 63;
    const int wave = tid >> 6;
    const int quad = lane >> 4;
    const int l16  = lane & 15;
    const int wm = wave & 1;
    const int wn = wave >> 1;
    const int mBase = blockIdx.y * BM;
    const int nBase = blockIdx.x * BN;

    tab[tid] = make_float2(NF4_C[tid >> 4], NF4_C[tid & 15]);

    f32x4 acc[4][4];
#pragma unroll
    for (int mi = 0; mi < 4; ++mi)
#pragma unroll
        for (int ni = 0; ni < 4; ++ni)
            acc[mi][ni] = (f32x4){0.f, 0.f, 0.f, 0.f};

    const int brow  = tid >> 1;
    const int bhalf = tid & 1;
    const int ng    = nBase + brow;

    for (int kt = 0; kt < IN_F / BK; ++kt) {
        const int k0 = kt * BK;
        __syncthreads();
#pragma unroll
        for (int i = 0; i < 4; ++i) {
            int gid = tid + i * 256;
            int row = gid >> 3;
            int c8  = gid & 7;
            const float4* src = reinterpret_cast<const float4*>(
                x + (size_t)(mBase + row) * IN_F + k0 + c8 * 8);
            float4 v0 = src[0];
            float4 v1 = src[1];
            u16x8 o;
            o[0] = f2bf(v0.x); o[1] = f2bf(v0.y); o[2] = f2bf(v0.z); o[3] = f2bf(v0.w);
            o[4] = f2bf(v1.x); o[5] = f2bf(v1.y); o[6] = f2bf(v1.z); o[7] = f2bf(v1.w);
            *reinterpret_cast<u16x8*>(&As[row * LDSS + c8 * 8]) = o;
        }
        {
            const float scale = absmax[(size_t)ng * 64 + (k0 >> 6)];
            const int4* bp = reinterpret_cast<const int4*>(
                packed + (size_t)ng * (IN_F / 2) + (k0 >> 1) + bhalf * 16);
            const int colw = bhalf * 32;
#pragma unroll
            for (int c = 0; c < 4; ++c) {
                int4 v = bp[c];
                int vs[4] = {v.x, v.y, v.z, v.w};
                unsigned int ow[4];
#pragma unroll
                for (int j = 0; j < 4; ++j) {
                    float2 t = tab[vs[j] & 0xFF];
                    ow[j] = (unsigned int)f2bf(t.x * scale)
                          | ((unsigned int)f2bf(t.y * scale) << 16);
                }
                *reinterpret_cast<uint4*>(&Bs[brow * LDSS + colw + c * 8]) =
                    *reinterpret_cast<const uint4*>(ow);
            }
        }
        __syncthreads();

#pragma unroll
        for (int kk = 0; kk < 2; ++kk) {
            const int kof = kk * 32 + quad * 8;
            s16x8 af[4], bfr[4];
#pragma unroll
            for (int mi = 0; mi < 4; ++mi)
                af[mi] = *reinterpret_cast<const s16x8*>(
                    &As[(wm * 64 + mi * 16 + l16) * LDSS + kof]);
#pragma unroll
            for (int ni = 0; ni < 4; ++ni)
                bfr[ni] = *reinterpret_cast<const s16x8*>(
                    &Bs[(wn * 64 + ni * 16 + l16) * LDSS + kof]);
#pragma unroll
            for (int mi = 0; mi < 4; ++mi)
#pragma unroll
                for (int ni = 0; ni < 4; ++ni)
                    acc[mi][ni] = __builtin_amdgcn_mfma_f32_16x16x32_bf16(
                        af[mi], bfr[ni], acc[mi][ni], 0, 0, 0);
        }
    }

    float bv[4];
#pragma unroll
    for (int ni = 0; ni < 4; ++ni)
        bv[ni] = bias[nBase + wn * 64 + ni * 16 + l16];
#pragma unroll
    for (int mi = 0; mi < 4; ++mi) {
        const int rbase = mBase + wm * 64 + mi * 16 + quad * 4;
#pragma unroll
        for (int ni = 0; ni < 4; ++ni) {
            const int col = nBase + wn * 64 + ni * 16 + l16;
#pragma unroll
            for (int r = 0; r < 4; ++r)
                out[(size_t)(rbase + r) * OUT_F + col] = acc[mi][ni][r] + bv[ni];
        }
    }
}

extern "C" void kernel_launch(void* const* d_in, const int* in_sizes, int n_in,
                              void* d_out, int out_size, void* d_ws, size_t ws_size,
                              hipStream_t stream) {
    const float* x      = (const float*)d_in[0];
    const int*   packed = (const int*)d_in[1];
    const float* absmax = (const float*)d_in[2];
    const float* bias   = (const float*)d_in[3];
    float* out = (float*)d_out;

    const size_t xb_bytes = (size_t)M_ROWS * IN_F * 2;          // 16,777,216
    const size_t wb_bytes = (size_t)OUT_F * IN_F * 2;           // 90,177,536
    if (ws_size >= xb_bytes + wb_bytes) {
        unsigned short* xb = (unsigned short*)d_ws;
        unsigned short* wb = (unsigned short*)((char*)d_ws + xb_bytes);
        prep_kernel<<<dim3(DQ_BLOCKS + CV_BLOCKS), dim3(256), 0, stream>>>(
            x, packed, absmax, xb, wb);
        gemm_bt_kernel<<<dim3(M_ROWS / BM, OUT_F / BN), dim3(256), 0, stream>>>(
            xb, wb, bias, out);
    } else {
        nf4_linear_fused<<<dim3(OUT_F / BN, M_ROWS / BM), dim3(256), 0, stream>>>(
            x, packed, absmax, bias, out);
    }
}

// Round 4
// 348.230 us; speedup vs baseline: 1.8126x; 1.1377x over previous
//
#include <hip/hip_runtime.h>
#include <hip/hip_bf16.h>

// Linear4bit NF4: y[2048,11008] = x[2048,4096] @ dequant(W)[11008,4096]^T + bias
// Phase 1 (merged, fully-coalesced): x fp32->bf16, NF4 dequant W->bf16 into d_ws.
// Phase 2: m97-style bf16 GEMM + XOR-swizzled LDS (kills the 16-way ds_read_b128
//   bank conflict while keeping global_load_lds's contiguous-dest contract:
//   swizzle is applied to the per-lane GLOBAL source address, readers un-swizzle).

#define IN_F   4096
#define OUT_F  11008
#define M_ROWS 2048
#define BM 128
#define BN 128
#define BK 64
#define LDSS 72   // fused-fallback padded stride

typedef short  s16x8 __attribute__((ext_vector_type(8)));
typedef unsigned short u16x8 __attribute__((ext_vector_type(8)));
typedef float  f32x4 __attribute__((ext_vector_type(4)));
typedef int    i32x4 __attribute__((ext_vector_type(4)));
typedef unsigned int u32x4 __attribute__((ext_vector_type(4)));

__device__ const float NF4_C[16] = {
    -1.0f, -0.6961928009986877f, -0.5250730514526367f, -0.39491748809814453f,
    -0.28444138169288635f, -0.18477343022823334f, -0.09105003625154495f, 0.0f,
    0.07958029955625534f, 0.16093020141124725f, 0.24611230194568634f,
    0.33791524171829224f, 0.44070982933044434f, 0.5626170039176941f,
    0.7229568362236023f, 1.0f};

static __device__ __forceinline__ unsigned short f2bf(float f) {
    union { float f; unsigned int u; } c;
    c.f = f;
    unsigned int u = c.u;
    u += 0x7fffu + ((u >> 16) & 1u);
    return (unsigned short)(u >> 16);
}

static __device__ __forceinline__ void gload_lds16(const void* g, void* l) {
    __builtin_amdgcn_global_load_lds(
        (const __attribute__((address_space(1))) void*)g,
        (__attribute__((address_space(3))) void*)l, 16, 0, 0);
}

// ---------------- phase 1 (merged, coalesced): dequant W + convert x ----------
// dequant: 5,636,096 int4-units (4 packed int32 = 8 weights -> 16B bf16 out),
//          2 units/thread, lane-contiguous (unit = blk*512 + tid, +256).
// convert: 2,097,152 float4-units (4 f32 -> 8B bf16 out), 2 units/thread.
#define DQ_BLOCKS 11008
#define CV_BLOCKS 4096

__global__ __launch_bounds__(256)
void prep_kernel(const float* __restrict__ x,
                 const int* __restrict__ packed,
                 const float* __restrict__ absmax,
                 unsigned short* __restrict__ xb,
                 unsigned short* __restrict__ wb) {
    if (blockIdx.x < DQ_BLOCKS) {
        __shared__ float tab_hi[256];
        __shared__ float tab_lo[256];
        tab_hi[threadIdx.x] = NF4_C[threadIdx.x >> 4];
        tab_lo[threadIdx.x] = NF4_C[threadIdx.x & 15];
        __syncthreads();

        const size_t u0 = (size_t)blockIdx.x * 512 + threadIdx.x;
#pragma unroll
        for (int h = 0; h < 2; ++h) {
            const size_t u = u0 + h * 256;
            i32x4 v = __builtin_nontemporal_load(
                reinterpret_cast<const i32x4*>(packed) + u);
            const float s = absmax[u >> 3];   // 8 weights/unit, 64-aligned blocks
            unsigned int ow[4];
#pragma unroll
            for (int j = 0; j < 4; ++j) {
                const int b = v[j] & 0xFF;
                ow[j] = (unsigned int)f2bf(tab_hi[b] * s)
                      | ((unsigned int)f2bf(tab_lo[b] * s) << 16);
            }
            *(reinterpret_cast<u32x4*>(wb) + u) = (u32x4){ow[0], ow[1], ow[2], ow[3]};
        }
    } else {
        const size_t u0 = (size_t)(blockIdx.x - DQ_BLOCKS) * 512 + threadIdx.x;
#pragma unroll
        for (int h = 0; h < 2; ++h) {
            const size_t u = u0 + h * 256;
            f32x4 v = __builtin_nontemporal_load(
                reinterpret_cast<const f32x4*>(x) + u);
            ushort4 o;
            o.x = f2bf(v[0]); o.y = f2bf(v[1]); o.z = f2bf(v[2]); o.w = f2bf(v[3]);
            *(reinterpret_cast<ushort4*>(xb) + u) = o;
        }
    }
}

// ---------------- phase 2: bf16 GEMM, m97 structure + XOR swizzle -------------
__global__ __launch_bounds__(256, 2)
void gemm_bt_kernel(const unsigned short* __restrict__ xb,   // [2048,4096] bf16
                    const unsigned short* __restrict__ wb,   // [11008,4096] bf16
                    const float* __restrict__ bias,
                    float* __restrict__ out) {
    __shared__ __align__(16) unsigned short As[BM * BK];
    __shared__ __align__(16) unsigned short Bs[BN * BK];

    const int tid  = threadIdx.x;
    const int lane = tid & 63;
    const int wave = tid >> 6;
    const int quad = lane >> 4;
    const int l16  = lane & 15;
    const int wm = wave & 1;
    const int wn = wave >> 1;

    // grid (M-tiles=16, N-tiles=86): consecutive blocks share a B-tile.
    const int mBase = blockIdx.x * BM;
    const int nBase = blockIdx.y * BN;

    // staging: LDS[row][c] holds global 16B-chunk (c ^ (row&7)) of that row.
    const int srow = tid >> 3;           // 0..31 (+32*i)
    const int sc   = tid & 7;            // LDS chunk (dest stays lane-contiguous)
    const int scS  = sc ^ (srow & 7);    // swizzled global source chunk

    f32x4 acc[4][4];
#pragma unroll
    for (int mi = 0; mi < 4; ++mi)
#pragma unroll
        for (int ni = 0; ni < 4; ++ni)
            acc[mi][ni] = (f32x4){0.f, 0.f, 0.f, 0.f};

    const unsigned short* aSrc = xb + (size_t)(mBase + srow) * IN_F + scS * 8;
    const unsigned short* bSrc = wb + (size_t)(nBase + srow) * IN_F + scS * 8;

    const int sw = l16 & 7;   // reader un-swizzle key (row&7 == l16&7)

    for (int kt = 0; kt < IN_F / BK; ++kt) {
        const int k0 = kt * BK;
        __syncthreads();
#pragma unroll
        for (int i = 0; i < 4; ++i)
            gload_lds16(aSrc + (size_t)i * 32 * IN_F + k0, &As[(i * 32 + srow) * BK + sc * 8]);
#pragma unroll
        for (int i = 0; i < 4; ++i)
            gload_lds16(bSrc + (size_t)i * 32 * IN_F + k0, &Bs[(i * 32 + srow) * BK + sc * 8]);
        __syncthreads();

#pragma unroll
        for (int kk = 0; kk < 2; ++kk) {
            const int q  = kk * 4 + quad;        // wanted global chunk
            const int rd = (q ^ sw) * 8;         // un-swizzled LDS offset (elems)
            s16x8 af[4], bfr[4];
#pragma unroll
            for (int mi = 0; mi < 4; ++mi)
                af[mi] = *reinterpret_cast<const s16x8*>(
                    &As[(wm * 64 + mi * 16 + l16) * BK + rd]);
#pragma unroll
            for (int ni = 0; ni < 4; ++ni)
                bfr[ni] = *reinterpret_cast<const s16x8*>(
                    &Bs[(wn * 64 + ni * 16 + l16) * BK + rd]);
#pragma unroll
            for (int mi = 0; mi < 4; ++mi)
#pragma unroll
                for (int ni = 0; ni < 4; ++ni)
                    acc[mi][ni] = __builtin_amdgcn_mfma_f32_16x16x32_bf16(
                        af[mi], bfr[ni], acc[mi][ni], 0, 0, 0);
        }
    }

    float bv[4];
#pragma unroll
    for (int ni = 0; ni < 4; ++ni)
        bv[ni] = bias[nBase + wn * 64 + ni * 16 + l16];
#pragma unroll
    for (int mi = 0; mi < 4; ++mi) {
        const int rbase = mBase + wm * 64 + mi * 16 + quad * 4;
#pragma unroll
        for (int ni = 0; ni < 4; ++ni) {
            const int col = nBase + wn * 64 + ni * 16 + l16;
#pragma unroll
            for (int r = 0; r < 4; ++r)
                __builtin_nontemporal_store(acc[mi][ni][r] + bv[ni],
                    &out[(size_t)(rbase + r) * OUT_F + col]);
        }
    }
}

// ---------------- fallback: fused kernel (small ws) ----------------
__global__ __launch_bounds__(256, 2)
void nf4_linear_fused(const float* __restrict__ x,
                      const int* __restrict__ packed,
                      const float* __restrict__ absmax,
                      const float* __restrict__ bias,
                      float* __restrict__ out) {
    __shared__ __align__(16) unsigned short As[BM * LDSS];
    __shared__ __align__(16) unsigned short Bs[BN * LDSS];
    __shared__ float2 tab[256];

    const int tid  = threadIdx.x;
    const int lane = tid & 63;
    const int wave = tid >> 6;
    const int quad = lane >> 4;
    const int l16  = lane & 15;
    const int wm = wave & 1;
    const int wn = wave >> 1;
    const int mBase = blockIdx.y * BM;
    const int nBase = blockIdx.x * BN;

    tab[tid] = make_float2(NF4_C[tid >> 4], NF4_C[tid & 15]);

    f32x4 acc[4][4];
#pragma unroll
    for (int mi = 0; mi < 4; ++mi)
#pragma unroll
        for (int ni = 0; ni < 4; ++ni)
            acc[mi][ni] = (f32x4){0.f, 0.f, 0.f, 0.f};

    const int brow  = tid >> 1;
    const int bhalf = tid & 1;
    const int ng    = nBase + brow;

    for (int kt = 0; kt < IN_F / BK; ++kt) {
        const int k0 = kt * BK;
        __syncthreads();
#pragma unroll
        for (int i = 0; i < 4; ++i) {
            int gid = tid + i * 256;
            int row = gid >> 3;
            int c8  = gid & 7;
            const float4* src = reinterpret_cast<const float4*>(
                x + (size_t)(mBase + row) * IN_F + k0 + c8 * 8);
            float4 v0 = src[0];
            float4 v1 = src[1];
            u16x8 o;
            o[0] = f2bf(v0.x); o[1] = f2bf(v0.y); o[2] = f2bf(v0.z); o[3] = f2bf(v0.w);
            o[4] = f2bf(v1.x); o[5] = f2bf(v1.y); o[6] = f2bf(v1.z); o[7] = f2bf(v1.w);
            *reinterpret_cast<u16x8*>(&As[row * LDSS + c8 * 8]) = o;
        }
        {
            const float scale = absmax[(size_t)ng * 64 + (k0 >> 6)];
            const int4* bp = reinterpret_cast<const int4*>(
                packed + (size_t)ng * (IN_F / 2) + (k0 >> 1) + bhalf * 16);
            const int colw = bhalf * 32;
#pragma unroll
            for (int c = 0; c < 4; ++c) {
                int4 v = bp[c];
                int vs[4] = {v.x, v.y, v.z, v.w};
                unsigned int ow[4];
#pragma unroll
                for (int j = 0; j < 4; ++j) {
                    float2 t = tab[vs[j] & 0xFF];
                    ow[j] = (unsigned int)f2bf(t.x * scale)
                          | ((unsigned int)f2bf(t.y * scale) << 16);
                }
                *reinterpret_cast<uint4*>(&Bs[brow * LDSS + colw + c * 8]) =
                    *reinterpret_cast<const uint4*>(ow);
            }
        }
        __syncthreads();

#pragma unroll
        for (int kk = 0; kk < 2; ++kk) {
            const int kof = kk * 32 + quad * 8;
            s16x8 af[4], bfr[4];
#pragma unroll
            for (int mi = 0; mi < 4; ++mi)
                af[mi] = *reinterpret_cast<const s16x8*>(
                    &As[(wm * 64 + mi * 16 + l16) * LDSS + kof]);
#pragma unroll
            for (int ni = 0; ni < 4; ++ni)
                bfr[ni] = *reinterpret_cast<const s16x8*>(
                    &Bs[(wn * 64 + ni * 16 + l16) * LDSS + kof]);
#pragma unroll
            for (int mi = 0; mi < 4; ++mi)
#pragma unroll
                for (int ni = 0; ni < 4; ++ni)
                    acc[mi][ni] = __builtin_amdgcn_mfma_f32_16x16x32_bf16(
                        af[mi], bfr[ni], acc[mi][ni], 0, 0, 0);
        }
    }

    float bv[4];
#pragma unroll
    for (int ni = 0; ni < 4; ++ni)
        bv[ni] = bias[nBase + wn * 64 + ni * 16 + l16];
#pragma unroll
    for (int mi = 0; mi < 4; ++mi) {
        const int rbase = mBase + wm * 64 + mi * 16 + quad * 4;
#pragma unroll
        for (int ni = 0; ni < 4; ++ni) {
            const int col = nBase + wn * 64 + ni * 16 + l16;
#pragma unroll
            for (int r = 0; r < 4; ++r)
                out[(size_t)(rbase + r) * OUT_F + col] = acc[mi][ni][r] + bv[ni];
        }
    }
}

extern "C" void kernel_launch(void* const* d_in, const int* in_sizes, int n_in,
                              void* d_out, int out_size, void* d_ws, size_t ws_size,
                              hipStream_t stream) {
    const float* x      = (const float*)d_in[0];
    const int*   packed = (const int*)d_in[1];
    const float* absmax = (const float*)d_in[2];
    const float* bias   = (const float*)d_in[3];
    float* out = (float*)d_out;

    const size_t xb_bytes = (size_t)M_ROWS * IN_F * 2;          // 16,777,216
    const size_t wb_bytes = (size_t)OUT_F * IN_F * 2;           // 90,177,536
    if (ws_size >= xb_bytes + wb_bytes) {
        unsigned short* xb = (unsigned short*)d_ws;
        unsigned short* wb = (unsigned short*)((char*)d_ws + xb_bytes);
        prep_kernel<<<dim3(DQ_BLOCKS + CV_BLOCKS), dim3(256), 0, stream>>>(
            x, packed, absmax, xb, wb);
        gemm_bt_kernel<<<dim3(M_ROWS / BM, OUT_F / BN), dim3(256), 0, stream>>>(
            xb, wb, bias, out);
    } else {
        nf4_linear_fused<<<dim3(OUT_F / BN, M_ROWS / BM), dim3(256), 0, stream>>>(
            x, packed, absmax, bias, out);
    }
}